// Round 23
// baseline (104.517 us; speedup 1.0000x reference)
//
#include <hip/hip_runtime.h>
#include <math.h>

#define D 64
#define S 4

typedef short short8 __attribute__((ext_vector_type(8)));
typedef float f32x4 __attribute__((ext_vector_type(4)));

// ---------------- workspace layout (float offsets) ----------------
#define WS_KEYS 0      // keys[S][D]
#define WS_ST   256    // st_norm[S]
#define WS_OUT1 272    // out1[D] (16B aligned)
#define WS_WF   512    // W bf16 fragments: 3 levels x 8 planes x 512 ushort (6144 floats)
#define WS_PART 8192   // per-block partials: nblk x 8 (4 f32 sums + 4 i32 lw)

#define TANH1(V_) fmaf(-2.f, __builtin_amdgcn_rcpf(__expf(2.f * (V_)) + 1.f), 1.f)

// exact 3-level truncation split: fp32 mantissa (24b) = 3 x 8b bf16 chunks
__global__ void k_prep(const float* __restrict__ slots,
                       const float* __restrict__ ss,
                       const float* __restrict__ Wk,
                       const float* __restrict__ bk,
                       const float* __restrict__ Wq,
                       float* __restrict__ ws) {
  int t = threadIdx.x;  // 256 threads
  __shared__ float sl[S][D];
  { int s = t >> 6, d = t & 63; sl[s][d] = slots[s * D + d]; }
  __syncthreads();
  {
    int s = t >> 6, d = t & 63;
    float acc = bk[d];
    for (int k = 0; k < D; ++k) acc = fmaf(sl[s][k], Wk[d * D + k], acc);
    ws[WS_KEYS + s * D + d] = tanhf(acc);
  }
  {
    unsigned short* wf = (unsigned short*)(ws + WS_WF);
    for (int idx = t; idx < 4096; idx += 256) {
      int p = idx >> 9, rem = idx & 511, lane = rem >> 3, j = rem & 7;
      int h = p >> 2, nb = p & 3;
      int n = nb * 16 + (lane & 15);
      int k = h * 32 + (lane >> 4) * 8 + j;
      float v = Wq[n * D + k];
      unsigned u1 = __float_as_uint(v);
      float r1 = v - __uint_as_float(u1 & 0xFFFF0000u);
      unsigned u2 = __float_as_uint(r1);
      float r2 = r1 - __uint_as_float(u2 & 0xFFFF0000u);
      unsigned u3 = __float_as_uint(r2);
      wf[idx] = (unsigned short)(u1 >> 16);
      wf[4096 + idx] = (unsigned short)(u2 >> 16);
      wf[8192 + idx] = (unsigned short)(u3 >> 16);
    }
  }
  if (t == 0) {
    float st[S]; float tot = 0.f;
    for (int s = 0; s < S; ++s) {
      float x = ss[s];
      float sp = log1pf(expf(-fabsf(x))) + fmaxf(x, 0.f);  // softplus
      st[s] = sp; tot += sp;
    }
    for (int s = 0; s < S; ++s) ws[WS_ST + s] = st[s] / tot;
  }
}

// split two float4 (8 k-values of this h) into 3 bf16 levels (trunc, exact)
#define SPLIT1(J_, V_) { \
  float v_ = (V_); \
  unsigned u1_ = __float_as_uint(v_); \
  float r1_ = v_ - __uint_as_float(u1_ & 0xFFFF0000u); \
  unsigned u2_ = __float_as_uint(r1_); \
  float r2_ = r1_ - __uint_as_float(u2_ & 0xFFFF0000u); \
  unsigned u3_ = __float_as_uint(r2_); \
  a1[J_] = (short)(u1_ >> 16); \
  a2[J_] = (short)(u2_ >> 16); \
  a3[J_] = (short)(u3_ >> 16); }

// MFMA kernel: W fragments in LDS (staged once/block) read per-(h,nb) right
// before use -> ~12 live frag regs instead of 96 persistent. Target: unified
// reg total <=128 -> 4 waves/SIMD (R23 occupancy theory). MFMA order per
// acc[nb] identical to R22 -> bitwise-same numerics.
__launch_bounds__(256)
__global__ void k_main(const float* __restrict__ item,
                       const float* __restrict__ ws,    // keys/st + wf
                       const float* __restrict__ bq,
                       float* red,                      // ws (partials out)
                       float* __restrict__ slot_weights,
                       float* __restrict__ selected,
                       int B) {
  __shared__ short8 lds_wf[1536];    // 24KB: [level*512 + plane*64 + lane]
  __shared__ float  lds_keys[256];
  __shared__ float  lds_bq[64];
  __shared__ float  red_sum[4][S];
  __shared__ int    red_lw[4][S];

  int t = threadIdx.x;
  int w = t >> 6, lane = t & 63;
  int lrow = lane & 15, g = lane >> 4;
  long base = (long)blockIdx.x * 512;

  // ---- stage W fragments + keys + bq into LDS (coalesced) ----
  {
    const short8* wfsrc = (const short8*)(ws + WS_WF);
    #pragma unroll
    for (int i = 0; i < 6; ++i) lds_wf[t + 256 * i] = wfsrc[t + 256 * i];
    lds_keys[t] = ws[WS_KEYS + t];
    if (t < 64) lds_bq[t] = bq[t];
  }

  float s0 = ws[WS_ST + 0], s1 = ws[WS_ST + 1];
  float s2 = ws[WS_ST + 2], s3 = ws[WS_ST + 3];

  // ---- prefetch iter 0 (issued before barrier; drained by it) ----
  const float4* xr = (const float4*)(item + (base + (long)w * 16 + lrow) * D);
  float4 p0 = xr[g * 2 + 0], p1 = xr[g * 2 + 1];
  float4 p2 = xr[8 + g * 2 + 0], p3 = xr[8 + g * 2 + 1];

  __syncthreads();

  float usum[S] = {0.f, 0.f, 0.f, 0.f};
  int   lmax[S] = {-1, -1, -1, -1};

  #pragma unroll 1
  for (int it = 0; it < 8; ++it) {
    long r0 = base + it * 64 + (long)w * 16;
    float4 c0 = p0, c1 = p1, c2 = p2, c3 = p3;
    if (it < 7) {                       // uniform-trip prefetch of iter+1
      const float4* xn = (const float4*)(item + (r0 + 64 + lrow) * D);
      p0 = xn[g * 2 + 0]; p1 = xn[g * 2 + 1];
      p2 = xn[8 + g * 2 + 0]; p3 = xn[8 + g * 2 + 1];
    }

    f32x4 acc[4];
    #pragma unroll
    for (int nb = 0; nb < 4; ++nb) acc[nb] = (f32x4){0.f, 0.f, 0.f, 0.f};

    #pragma unroll
    for (int h = 0; h < 2; ++h) {
      float4 xa = (h == 0) ? c0 : c2;
      float4 xb = (h == 0) ? c1 : c3;
      short8 a1, a2, a3;
      SPLIT1(0, xa.x) SPLIT1(1, xa.y) SPLIT1(2, xa.z) SPLIT1(3, xa.w)
      SPLIT1(4, xb.x) SPLIT1(5, xb.y) SPLIT1(6, xb.z) SPLIT1(7, xb.w)

      #pragma unroll
      for (int nb = 0; nb < 4; ++nb) {
        int pl = (h * 4 + nb) * 64 + lane;
        short8 b1 = lds_wf[pl];
        short8 b2 = lds_wf[512 + pl];
        short8 b3 = lds_wf[1024 + pl];
        acc[nb] = __builtin_amdgcn_mfma_f32_16x16x32_bf16(a1, b1, acc[nb], 0, 0, 0);
        acc[nb] = __builtin_amdgcn_mfma_f32_16x16x32_bf16(a1, b2, acc[nb], 0, 0, 0);
        acc[nb] = __builtin_amdgcn_mfma_f32_16x16x32_bf16(a2, b1, acc[nb], 0, 0, 0);
        acc[nb] = __builtin_amdgcn_mfma_f32_16x16x32_bf16(a1, b3, acc[nb], 0, 0, 0);
        acc[nb] = __builtin_amdgcn_mfma_f32_16x16x32_bf16(a3, b1, acc[nb], 0, 0, 0);
        acc[nb] = __builtin_amdgcn_mfma_f32_16x16x32_bf16(a2, b2, acc[nb], 0, 0, 0);
      }
    }

    // epilogue: tanh + partial sims (kf/bq from LDS, transient regs)
    float ps[4][4];
    #pragma unroll
    for (int r_ = 0; r_ < 4; ++r_)
      #pragma unroll
      for (int s = 0; s < S; ++s) ps[r_][s] = 0.f;
    #pragma unroll
    for (int nb = 0; nb < 4; ++nb) {
      float bqn = lds_bq[nb * 16 + lrow];
      float k0v = lds_keys[0 * D + nb * 16 + lrow];
      float k1v = lds_keys[1 * D + nb * 16 + lrow];
      float k2v = lds_keys[2 * D + nb * 16 + lrow];
      float k3v = lds_keys[3 * D + nb * 16 + lrow];
      #pragma unroll
      for (int r_ = 0; r_ < 4; ++r_) {
        float q = TANH1(acc[nb][r_] + bqn);
        ps[r_][0] = fmaf(q, k0v, ps[r_][0]);
        ps[r_][1] = fmaf(q, k1v, ps[r_][1]);
        ps[r_][2] = fmaf(q, k2v, ps[r_][2]);
        ps[r_][3] = fmaf(q, k3v, ps[r_][3]);
      }
    }
    #pragma unroll
    for (int m_ = 1; m_ <= 8; m_ <<= 1)
      #pragma unroll
      for (int r_ = 0; r_ < 4; ++r_)
        #pragma unroll
        for (int s = 0; s < S; ++s) ps[r_][s] += __shfl_xor(ps[r_][s], m_);

    bool act = lrow < 4;
    float q0 = ps[0][0], q1 = ps[0][1], q2 = ps[0][2], q3 = ps[0][3];
    if (lrow == 1)      { q0 = ps[1][0]; q1 = ps[1][1]; q2 = ps[1][2]; q3 = ps[1][3]; }
    else if (lrow == 2) { q0 = ps[2][0]; q1 = ps[2][1]; q2 = ps[2][2]; q3 = ps[2][3]; }
    else if (lrow == 3) { q0 = ps[3][0]; q1 = ps[3][1]; q2 = ps[3][2]; q3 = ps[3][3]; }
    long grow = r0 + g * 4 + lrow;

    if (act) {
      float m = fmaxf(fmaxf(q0, q1), fmaxf(q2, q3));
      float e0 = expf(q0 - m), e1 = expf(q1 - m), e2 = expf(q2 - m), e3 = expf(q3 - m);
      float se = e0 + e1 + e2 + e3;
      float w0 = e0 / se, w1 = e1 / se, w2 = e2 / se, w3 = e3 / se;
      *(float4*)(slot_weights + grow * S) = make_float4(w0, w1, w2, w3);
      float u0 = w0 * s0, u1 = w1 * s1, u2 = w2 * s2, u3 = w3 * s3;
      float us = u0 + u1 + u2 + u3;
      u0 /= us; u1 /= us; u2 /= us; u3 /= us;
      int sel = 0; float best = u0;
      if (u1 > best) { best = u1; sel = 1; }
      if (u2 > best) { best = u2; sel = 2; }
      if (u3 > best) { best = u3; sel = 3; }
      selected[grow] = (float)sel;
      usum[0] += u0; usum[1] += u1; usum[2] += u2; usum[3] += u3;
      #pragma unroll
      for (int s = 0; s < S; ++s)
        if (sel == s && (int)grow > lmax[s]) lmax[s] = (int)grow;
    }
  }

  // ---- block reduction -> plain-store per-block partials (no atomics) ----
  #pragma unroll
  for (int off = 32; off > 0; off >>= 1) {
    #pragma unroll
    for (int s = 0; s < S; ++s) {
      usum[s] += __shfl_down(usum[s], off);
      int m = __shfl_down(lmax[s], off);
      lmax[s] = lmax[s] > m ? lmax[s] : m;
    }
  }
  if (lane == 0) {
    #pragma unroll
    for (int s = 0; s < S; ++s) { red_sum[w][s] = usum[s]; red_lw[w][s] = lmax[s]; }
  }
  __syncthreads();
  if (t < S) {
    float tot = red_sum[0][t] + red_sum[1][t] + red_sum[2][t] + red_sum[3][t];
    int lm = red_lw[0][t];
    if (red_lw[1][t] > lm) lm = red_lw[1][t];
    if (red_lw[2][t] > lm) lm = red_lw[2][t];
    if (red_lw[3][t] > lm) lm = red_lw[3][t];
    float* part = red + WS_PART + (long)blockIdx.x * 8;
    part[t] = tot;
    ((int*)part)[4 + t] = lm;
  }
}

__global__ void k_final(const float* __restrict__ item,
                        const float* __restrict__ slots,
                        const float* __restrict__ usage,
                        const float* __restrict__ Wv,
                        const float* __restrict__ bv,
                        float* ws,
                        float* __restrict__ out_ns,
                        float* __restrict__ out_nu,
                        int B, int nblk) {
  int t = threadIdx.x;  // 256 threads
  int w = t >> 6, lane = t & 63, d = t & 63;
  __shared__ float rs[4][S];
  __shared__ int   rl[4][S];
  __shared__ float s_sums[S];
  __shared__ int   s_lw[S];
  __shared__ float mean[D];
  __shared__ float part4[4][D];

  // ---- phase 1: reduce per-block partials (plain loads) ----
  float ls[S] = {0.f, 0.f, 0.f, 0.f};
  int   ll[S] = {-1, -1, -1, -1};
  const float* part = ws + WS_PART;
  for (int i = t; i < nblk; i += 256) {
    const float* p = part + (long)i * 8;
    ls[0] += p[0]; ls[1] += p[1]; ls[2] += p[2]; ls[3] += p[3];
    const int* pi = (const int*)p + 4;
    ll[0] = ll[0] > pi[0] ? ll[0] : pi[0];
    ll[1] = ll[1] > pi[1] ? ll[1] : pi[1];
    ll[2] = ll[2] > pi[2] ? ll[2] : pi[2];
    ll[3] = ll[3] > pi[3] ? ll[3] : pi[3];
  }
  #pragma unroll
  for (int off = 32; off > 0; off >>= 1) {
    #pragma unroll
    for (int s = 0; s < S; ++s) {
      ls[s] += __shfl_down(ls[s], off);
      int m = __shfl_down(ll[s], off);
      ll[s] = ll[s] > m ? ll[s] : m;
    }
  }
  if (lane == 0) {
    #pragma unroll
    for (int s = 0; s < S; ++s) { rs[w][s] = ls[s]; rl[w][s] = ll[s]; }
  }
  __syncthreads();
  if (t < S) {
    s_sums[t] = rs[0][t] + rs[1][t] + rs[2][t] + rs[3][t];
    int lm = rl[0][t];
    if (rl[1][t] > lm) lm = rl[1][t];
    if (rl[2][t] > lm) lm = rl[2][t];
    if (rl[3][t] > lm) lm = rl[3][t];
    s_lw[t] = lm;
  }
  __syncthreads();

  // ---- phase 2: new_slots / mean / out1 / new_usage ----
  if (w == 0) {
    float nsv[S];
    for (int s = 0; s < S; ++s) {
      int wr = s_lw[s];
      float v = (wr >= 0) ? item[(size_t)wr * D + d] : slots[s * D + d];
      nsv[s] = v;
      out_ns[s * D + d] = v;
    }
    mean[d] = (nsv[0] + nsv[1] + nsv[2] + nsv[3]) * 0.25f;
  }
  __syncthreads();
  float acc = 0.f;
  for (int k = w * 16; k < w * 16 + 16; ++k) acc = fmaf(mean[k], Wv[d * D + k], acc);
  part4[w][d] = acc;
  __syncthreads();
  if (w == 0) {
    float a = part4[0][d] + part4[1][d] + part4[2][d] + part4[3][d] + bv[d];
    ws[WS_OUT1 + d] = tanhf(a);
    if (d < S) out_nu[d] = usage[d] * 0.9f + s_sums[d] / (float)B;
  }
}

__global__ void k_bcast(const float* __restrict__ ws,
                        float4* __restrict__ out, long n4) {
  __shared__ float4 o4[16];
  if (threadIdx.x < 16) o4[threadIdx.x] = ((const float4*)(ws + WS_OUT1))[threadIdx.x];
  __syncthreads();
  long i = (long)blockIdx.x * blockDim.x + threadIdx.x;
  long stride = (long)gridDim.x * blockDim.x;
  for (; i < n4; i += stride) out[i] = o4[i & 15];
}

extern "C" void kernel_launch(void* const* d_in, const int* in_sizes, int n_in,
                              void* d_out, int out_size, void* d_ws, size_t ws_size,
                              hipStream_t stream) {
  const float* item  = (const float*)d_in[0];
  const float* slots = (const float*)d_in[1];
  const float* ss    = (const float*)d_in[2];
  const float* usage = (const float*)d_in[3];
  const float* Wq    = (const float*)d_in[4];
  const float* bq    = (const float*)d_in[5];
  const float* Wk    = (const float*)d_in[6];
  const float* bk    = (const float*)d_in[7];
  const float* Wv    = (const float*)d_in[8];
  const float* bv    = (const float*)d_in[9];
  int B = in_sizes[0] / D;
  float* ws = (float*)d_ws;

  float* out_output       = (float*)d_out;
  float* out_new_slots    = out_output + (size_t)B * D;
  float* out_new_usage    = out_new_slots + S * D;
  float* out_selected     = out_new_usage + S;
  float* out_slot_weights = out_selected + B;

  int nblk = B / 512;
  k_prep<<<1, 256, 0, stream>>>(slots, ss, Wk, bk, Wq, ws);
  k_main<<<nblk, 256, 0, stream>>>(
      item, ws, bq, ws, out_slot_weights, out_selected, B);
  k_final<<<1, 256, 0, stream>>>(item, slots, usage, Wv, bv, ws,
                                 out_new_slots, out_new_usage, B, nblk);
  long n4 = (long)B * D / 4;
  k_bcast<<<2048, 256, 0, stream>>>(ws, (float4*)out_output, n4);
}

// Round 24
// 103.133 us; speedup vs baseline: 1.0134x; 1.0134x over previous
//
#include <hip/hip_runtime.h>
#include <math.h>

#define D 64
#define S 4

typedef short short8 __attribute__((ext_vector_type(8)));
typedef float f32x4 __attribute__((ext_vector_type(4)));

// ---------------- workspace layout (float offsets) ----------------
#define WS_KEYS 0      // keys[S][D]
#define WS_ST   256    // st_norm[S]
#define WS_OUT1 272    // out1[D] (16B aligned)
#define WS_WF   512    // W bf16 fragments: 3 levels x 8 planes x 512 ushort (6144 floats)
#define WS_PART 8192   // per-block partials: nblk x 8 (4 f32 sums + 4 i32 lw)

#define TANH1(V_) fmaf(-2.f, __builtin_amdgcn_rcpf(__expf(2.f * (V_)) + 1.f), 1.f)

// exact 3-level truncation split: fp32 mantissa (24b) = 3 x 8b bf16 chunks
__global__ void k_prep(const float* __restrict__ slots,
                       const float* __restrict__ ss,
                       const float* __restrict__ Wk,
                       const float* __restrict__ bk,
                       const float* __restrict__ Wq,
                       float* __restrict__ ws) {
  int t = threadIdx.x;  // 256 threads
  __shared__ float sl[S][D];
  { int s = t >> 6, d = t & 63; sl[s][d] = slots[s * D + d]; }
  __syncthreads();
  {
    int s = t >> 6, d = t & 63;
    float acc = bk[d];
    for (int k = 0; k < D; ++k) acc = fmaf(sl[s][k], Wk[d * D + k], acc);
    ws[WS_KEYS + s * D + d] = tanhf(acc);
  }
  {
    unsigned short* wf = (unsigned short*)(ws + WS_WF);
    for (int idx = t; idx < 4096; idx += 256) {
      int p = idx >> 9, rem = idx & 511, lane = rem >> 3, j = rem & 7;
      int h = p >> 2, nb = p & 3;
      int n = nb * 16 + (lane & 15);
      int k = h * 32 + (lane >> 4) * 8 + j;
      float v = Wq[n * D + k];
      unsigned u1 = __float_as_uint(v);
      float r1 = v - __uint_as_float(u1 & 0xFFFF0000u);
      unsigned u2 = __float_as_uint(r1);
      float r2 = r1 - __uint_as_float(u2 & 0xFFFF0000u);
      unsigned u3 = __float_as_uint(r2);
      wf[idx] = (unsigned short)(u1 >> 16);
      wf[4096 + idx] = (unsigned short)(u2 >> 16);
      wf[8192 + idx] = (unsigned short)(u3 >> 16);
    }
  }
  if (t == 0) {
    float st[S]; float tot = 0.f;
    for (int s = 0; s < S; ++s) {
      float x = ss[s];
      float sp = log1pf(expf(-fabsf(x))) + fmaxf(x, 0.f);  // softplus
      st[s] = sp; tot += sp;
    }
    for (int s = 0; s < S; ++s) ws[WS_ST + s] = st[s] / tot;
  }
}

#define SPLITJ(H_, J_, V_) { \
  float v_ = (V_); \
  unsigned u1_ = __float_as_uint(v_); \
  float r1_ = v_ - __uint_as_float(u1_ & 0xFFFF0000u); \
  unsigned u2_ = __float_as_uint(r1_); \
  float r2_ = r1_ - __uint_as_float(u2_ & 0xFFFF0000u); \
  unsigned u3_ = __float_as_uint(r2_); \
  a1[H_][J_] = (short)(u1_ >> 16); \
  a2[H_][J_] = (short)(u2_ >> 16); \
  a3[H_][J_] = (short)(u3_ >> 16); }

// epilogue for ONE finished tile (acc set ACC_, tile base row R0P_).
// Identical ops/order to R22's epilogue.
#define EPILOGUE(ACC_, R0P_) { \
  float ps[4][4]; \
  _Pragma("unroll") \
  for (int r_ = 0; r_ < 4; ++r_) \
    _Pragma("unroll") \
    for (int s = 0; s < S; ++s) ps[r_][s] = 0.f; \
  _Pragma("unroll") \
  for (int nb = 0; nb < 4; ++nb) \
    _Pragma("unroll") \
    for (int r_ = 0; r_ < 4; ++r_) { \
      float q = TANH1(ACC_[nb][r_] + bqv[nb]); \
      _Pragma("unroll") \
      for (int s = 0; s < S; ++s) ps[r_][s] = fmaf(q, kf[s][nb], ps[r_][s]); \
    } \
  _Pragma("unroll") \
  for (int m_ = 1; m_ <= 8; m_ <<= 1) \
    _Pragma("unroll") \
    for (int r_ = 0; r_ < 4; ++r_) \
      _Pragma("unroll") \
      for (int s = 0; s < S; ++s) ps[r_][s] += __shfl_xor(ps[r_][s], m_); \
  bool act = lrow < 4; \
  float q0 = ps[0][0], q1 = ps[0][1], q2 = ps[0][2], q3 = ps[0][3]; \
  if (lrow == 1)      { q0 = ps[1][0]; q1 = ps[1][1]; q2 = ps[1][2]; q3 = ps[1][3]; } \
  else if (lrow == 2) { q0 = ps[2][0]; q1 = ps[2][1]; q2 = ps[2][2]; q3 = ps[2][3]; } \
  else if (lrow == 3) { q0 = ps[3][0]; q1 = ps[3][1]; q2 = ps[3][2]; q3 = ps[3][3]; } \
  long grow = (R0P_) + g * 4 + lrow; \
  if (act) { \
    float m = fmaxf(fmaxf(q0, q1), fmaxf(q2, q3)); \
    float e0 = expf(q0 - m), e1 = expf(q1 - m), e2 = expf(q2 - m), e3 = expf(q3 - m); \
    float se = e0 + e1 + e2 + e3; \
    float w0 = e0 / se, w1 = e1 / se, w2 = e2 / se, w3 = e3 / se; \
    *(float4*)(slot_weights + grow * S) = make_float4(w0, w1, w2, w3); \
    float u0 = w0 * s0, u1 = w1 * s1, u2 = w2 * s2, u3 = w3 * s3; \
    float us = u0 + u1 + u2 + u3; \
    u0 /= us; u1 /= us; u2 /= us; u3 /= us; \
    int sel = 0; float best = u0; \
    if (u1 > best) { best = u1; sel = 1; } \
    if (u2 > best) { best = u2; sel = 2; } \
    if (u3 > best) { best = u3; sel = 3; } \
    selected[grow] = (float)sel; \
    usum[0] += u0; usum[1] += u1; usum[2] += u2; usum[3] += u3; \
    _Pragma("unroll") \
    for (int s = 0; s < S; ++s) \
      if (sel == s && (int)grow > lmax[s]) lmax[s] = (int)grow; \
  } }

// MFMA kernel, manual lag-1 software pipeline: loop body issues tile N's
// split+MFMA (-> accN), then runs tile N-1's epilogue (reads accP, register-
// independent of accN) while the MFMA chains retire; then accP <- accN.
// Per-tile op order identical to R22 -> bitwise-same outputs.
__launch_bounds__(256)
__global__ void k_main(const float* __restrict__ item,
                       const float* __restrict__ ws,    // keys/st + wf
                       const float* __restrict__ bq,
                       float* red,                      // ws (partials out)
                       float* __restrict__ slot_weights,
                       float* __restrict__ selected,
                       int B) {
  __shared__ float red_sum[4][S];
  __shared__ int   red_lw[4][S];

  int t = threadIdx.x;
  int w = t >> 6, lane = t & 63;
  int lrow = lane & 15, g = lane >> 4;
  long base = (long)blockIdx.x * 512;

  // ---- persistent W fragments: 24 short8 = 96 VGPR ----
  const short8* wfv = (const short8*)(ws + WS_WF);
  short8 B1[2][4], B2[2][4], B3[2][4];
  #pragma unroll
  for (int h = 0; h < 2; ++h)
    #pragma unroll
    for (int nb = 0; nb < 4; ++nb) {
      B1[h][nb] = wfv[(h * 4 + nb) * 64 + lane];
      B2[h][nb] = wfv[512 + (h * 4 + nb) * 64 + lane];
      B3[h][nb] = wfv[1024 + (h * 4 + nb) * 64 + lane];
    }

  float kf[4][4], bqv[4];
  #pragma unroll
  for (int nb = 0; nb < 4; ++nb) {
    bqv[nb] = bq[nb * 16 + lrow];
    #pragma unroll
    for (int s = 0; s < S; ++s) kf[s][nb] = ws[WS_KEYS + s * D + nb * 16 + lrow];
  }
  float s0 = ws[WS_ST + 0], s1 = ws[WS_ST + 1];
  float s2 = ws[WS_ST + 2], s3 = ws[WS_ST + 3];

  float usum[S] = {0.f, 0.f, 0.f, 0.f};
  int   lmax[S] = {-1, -1, -1, -1};

  // ---- prefetch iter 0 ----
  const float4* xr = (const float4*)(item + (base + (long)w * 16 + lrow) * D);
  float4 p0 = xr[g * 2 + 0], p1 = xr[g * 2 + 1];
  float4 p2 = xr[8 + g * 2 + 0], p3 = xr[8 + g * 2 + 1];

  f32x4 accP[4];            // previous tile's accumulators (pipeline stage)
  long r0P = base + (long)w * 16;

  #pragma unroll 1
  for (int it = 0; it < 8; ++it) {
    long r0 = base + it * 64 + (long)w * 16;
    float4 c0 = p0, c1 = p1, c2 = p2, c3 = p3;
    if (it < 7) {                       // uniform-trip prefetch of iter+1
      const float4* xn = (const float4*)(item + (r0 + 64 + lrow) * D);
      p0 = xn[g * 2 + 0]; p1 = xn[g * 2 + 1];
      p2 = xn[8 + g * 2 + 0]; p3 = xn[8 + g * 2 + 1];
    }

    short8 a1[2], a2[2], a3[2];
    SPLITJ(0, 0, c0.x) SPLITJ(0, 1, c0.y) SPLITJ(0, 2, c0.z) SPLITJ(0, 3, c0.w)
    SPLITJ(0, 4, c1.x) SPLITJ(0, 5, c1.y) SPLITJ(0, 6, c1.z) SPLITJ(0, 7, c1.w)
    SPLITJ(1, 0, c2.x) SPLITJ(1, 1, c2.y) SPLITJ(1, 2, c2.z) SPLITJ(1, 3, c2.w)
    SPLITJ(1, 4, c3.x) SPLITJ(1, 5, c3.y) SPLITJ(1, 6, c3.z) SPLITJ(1, 7, c3.w)

    f32x4 accN[4];
    #pragma unroll
    for (int nb = 0; nb < 4; ++nb) accN[nb] = (f32x4){0.f, 0.f, 0.f, 0.f};

    #pragma unroll
    for (int h = 0; h < 2; ++h) {
      #pragma unroll
      for (int nb = 0; nb < 4; ++nb) {
        accN[nb] = __builtin_amdgcn_mfma_f32_16x16x32_bf16(a1[h], B1[h][nb], accN[nb], 0, 0, 0);
        accN[nb] = __builtin_amdgcn_mfma_f32_16x16x32_bf16(a1[h], B2[h][nb], accN[nb], 0, 0, 0);
        accN[nb] = __builtin_amdgcn_mfma_f32_16x16x32_bf16(a2[h], B1[h][nb], accN[nb], 0, 0, 0);
        accN[nb] = __builtin_amdgcn_mfma_f32_16x16x32_bf16(a1[h], B3[h][nb], accN[nb], 0, 0, 0);
        accN[nb] = __builtin_amdgcn_mfma_f32_16x16x32_bf16(a3[h], B1[h][nb], accN[nb], 0, 0, 0);
        accN[nb] = __builtin_amdgcn_mfma_f32_16x16x32_bf16(a2[h], B2[h][nb], accN[nb], 0, 0, 0);
      }
    }

    // previous tile's epilogue overlaps this tile's MFMA retirement
    if (it > 0) { EPILOGUE(accP, r0P) }

    #pragma unroll
    for (int nb = 0; nb < 4; ++nb) accP[nb] = accN[nb];
    r0P = r0;
  }
  // drain: last tile's epilogue
  EPILOGUE(accP, r0P)

  // ---- block reduction -> plain-store per-block partials (no atomics) ----
  #pragma unroll
  for (int off = 32; off > 0; off >>= 1) {
    #pragma unroll
    for (int s = 0; s < S; ++s) {
      usum[s] += __shfl_down(usum[s], off);
      int m = __shfl_down(lmax[s], off);
      lmax[s] = lmax[s] > m ? lmax[s] : m;
    }
  }
  if (lane == 0) {
    #pragma unroll
    for (int s = 0; s < S; ++s) { red_sum[w][s] = usum[s]; red_lw[w][s] = lmax[s]; }
  }
  __syncthreads();
  if (t < S) {
    float tot = red_sum[0][t] + red_sum[1][t] + red_sum[2][t] + red_sum[3][t];
    int lm = red_lw[0][t];
    if (red_lw[1][t] > lm) lm = red_lw[1][t];
    if (red_lw[2][t] > lm) lm = red_lw[2][t];
    if (red_lw[3][t] > lm) lm = red_lw[3][t];
    float* part = red + WS_PART + (long)blockIdx.x * 8;
    part[t] = tot;
    ((int*)part)[4 + t] = lm;
  }
}

__global__ void k_final(const float* __restrict__ item,
                        const float* __restrict__ slots,
                        const float* __restrict__ usage,
                        const float* __restrict__ Wv,
                        const float* __restrict__ bv,
                        float* ws,
                        float* __restrict__ out_ns,
                        float* __restrict__ out_nu,
                        int B, int nblk) {
  int t = threadIdx.x;  // 256 threads
  int w = t >> 6, lane = t & 63, d = t & 63;
  __shared__ float rs[4][S];
  __shared__ int   rl[4][S];
  __shared__ float s_sums[S];
  __shared__ int   s_lw[S];
  __shared__ float mean[D];
  __shared__ float part4[4][D];

  // ---- phase 1: reduce per-block partials (plain loads) ----
  float ls[S] = {0.f, 0.f, 0.f, 0.f};
  int   ll[S] = {-1, -1, -1, -1};
  const float* part = ws + WS_PART;
  for (int i = t; i < nblk; i += 256) {
    const float* p = part + (long)i * 8;
    ls[0] += p[0]; ls[1] += p[1]; ls[2] += p[2]; ls[3] += p[3];
    const int* pi = (const int*)p + 4;
    ll[0] = ll[0] > pi[0] ? ll[0] : pi[0];
    ll[1] = ll[1] > pi[1] ? ll[1] : pi[1];
    ll[2] = ll[2] > pi[2] ? ll[2] : pi[2];
    ll[3] = ll[3] > pi[3] ? ll[3] : pi[3];
  }
  #pragma unroll
  for (int off = 32; off > 0; off >>= 1) {
    #pragma unroll
    for (int s = 0; s < S; ++s) {
      ls[s] += __shfl_down(ls[s], off);
      int m = __shfl_down(ll[s], off);
      ll[s] = ll[s] > m ? ll[s] : m;
    }
  }
  if (lane == 0) {
    #pragma unroll
    for (int s = 0; s < S; ++s) { rs[w][s] = ls[s]; rl[w][s] = ll[s]; }
  }
  __syncthreads();
  if (t < S) {
    s_sums[t] = rs[0][t] + rs[1][t] + rs[2][t] + rs[3][t];
    int lm = rl[0][t];
    if (rl[1][t] > lm) lm = rl[1][t];
    if (rl[2][t] > lm) lm = rl[2][t];
    if (rl[3][t] > lm) lm = rl[3][t];
    s_lw[t] = lm;
  }
  __syncthreads();

  // ---- phase 2: new_slots / mean / out1 / new_usage ----
  if (w == 0) {
    float nsv[S];
    for (int s = 0; s < S; ++s) {
      int wr = s_lw[s];
      float v = (wr >= 0) ? item[(size_t)wr * D + d] : slots[s * D + d];
      nsv[s] = v;
      out_ns[s * D + d] = v;
    }
    mean[d] = (nsv[0] + nsv[1] + nsv[2] + nsv[3]) * 0.25f;
  }
  __syncthreads();
  float acc = 0.f;
  for (int k = w * 16; k < w * 16 + 16; ++k) acc = fmaf(mean[k], Wv[d * D + k], acc);
  part4[w][d] = acc;
  __syncthreads();
  if (w == 0) {
    float a = part4[0][d] + part4[1][d] + part4[2][d] + part4[3][d] + bv[d];
    ws[WS_OUT1 + d] = tanhf(a);
    if (d < S) out_nu[d] = usage[d] * 0.9f + s_sums[d] / (float)B;
  }
}

__global__ void k_bcast(const float* __restrict__ ws,
                        float4* __restrict__ out, long n4) {
  __shared__ float4 o4[16];
  if (threadIdx.x < 16) o4[threadIdx.x] = ((const float4*)(ws + WS_OUT1))[threadIdx.x];
  __syncthreads();
  long i = (long)blockIdx.x * blockDim.x + threadIdx.x;
  long stride = (long)gridDim.x * blockDim.x;
  for (; i < n4; i += stride) out[i] = o4[i & 15];
}

extern "C" void kernel_launch(void* const* d_in, const int* in_sizes, int n_in,
                              void* d_out, int out_size, void* d_ws, size_t ws_size,
                              hipStream_t stream) {
  const float* item  = (const float*)d_in[0];
  const float* slots = (const float*)d_in[1];
  const float* ss    = (const float*)d_in[2];
  const float* usage = (const float*)d_in[3];
  const float* Wq    = (const float*)d_in[4];
  const float* bq    = (const float*)d_in[5];
  const float* Wk    = (const float*)d_in[6];
  const float* bk    = (const float*)d_in[7];
  const float* Wv    = (const float*)d_in[8];
  const float* bv    = (const float*)d_in[9];
  int B = in_sizes[0] / D;
  float* ws = (float*)d_ws;

  float* out_output       = (float*)d_out;
  float* out_new_slots    = out_output + (size_t)B * D;
  float* out_new_usage    = out_new_slots + S * D;
  float* out_selected     = out_new_usage + S;
  float* out_slot_weights = out_selected + B;

  int nblk = B / 512;
  k_prep<<<1, 256, 0, stream>>>(slots, ss, Wk, bk, Wq, ws);
  k_main<<<nblk, 256, 0, stream>>>(
      item, ws, bq, ws, out_slot_weights, out_selected, B);
  k_final<<<1, 256, 0, stream>>>(item, slots, usage, Wv, bv, ws,
                                 out_new_slots, out_new_usage, B, nblk);
  long n4 = (long)B * D / 4;
  k_bcast<<<2048, 256, 0, stream>>>(ws, (float4*)out_output, n4);
}

// Round 26
// 99.245 us; speedup vs baseline: 1.0531x; 1.0392x over previous
//
#include <hip/hip_runtime.h>
#include <math.h>

#define D 64
#define S 4

typedef short short8 __attribute__((ext_vector_type(8)));
typedef float f32x4 __attribute__((ext_vector_type(4)));

// ---------------- workspace layout (float offsets) ----------------
#define WS_KEYS 0      // keys[S][D]
#define WS_ST   256    // st_norm[S]
#define WS_OUT1 272    // out1[D] (16B aligned)
#define WS_WF   512    // W bf16 fragments: 3 levels x 8 planes x 512 ushort (6144 floats)
#define WS_PART 8192   // per-block partials: nblk x 8 (4 f32 sums + 4 i32 lw)

#define TANH1(V_) fmaf(-2.f, __builtin_amdgcn_rcpf(__expf(2.f * (V_)) + 1.f), 1.f)

// exact 3-level truncation split: fp32 mantissa (24b) = 3 x 8b bf16 chunks
__global__ void k_prep(const float* __restrict__ slots,
                       const float* __restrict__ ss,
                       const float* __restrict__ Wk,
                       const float* __restrict__ bk,
                       const float* __restrict__ Wq,
                       float* __restrict__ ws) {
  int t = threadIdx.x;  // 256 threads
  __shared__ float sl[S][D];
  { int s = t >> 6, d = t & 63; sl[s][d] = slots[s * D + d]; }
  __syncthreads();
  {
    int s = t >> 6, d = t & 63;
    float acc = bk[d];
    for (int k = 0; k < D; ++k) acc = fmaf(sl[s][k], Wk[d * D + k], acc);
    ws[WS_KEYS + s * D + d] = tanhf(acc);
  }
  {
    unsigned short* wf = (unsigned short*)(ws + WS_WF);
    for (int idx = t; idx < 4096; idx += 256) {
      int p = idx >> 9, rem = idx & 511, lane = rem >> 3, j = rem & 7;
      int h = p >> 2, nb = p & 3;
      int n = nb * 16 + (lane & 15);
      int k = h * 32 + (lane >> 4) * 8 + j;
      float v = Wq[n * D + k];
      unsigned u1 = __float_as_uint(v);
      float r1 = v - __uint_as_float(u1 & 0xFFFF0000u);
      unsigned u2 = __float_as_uint(r1);
      float r2 = r1 - __uint_as_float(u2 & 0xFFFF0000u);
      unsigned u3 = __float_as_uint(r2);
      wf[idx] = (unsigned short)(u1 >> 16);
      wf[4096 + idx] = (unsigned short)(u2 >> 16);
      wf[8192 + idx] = (unsigned short)(u3 >> 16);
    }
  }
  if (t == 0) {
    float st[S]; float tot = 0.f;
    for (int s = 0; s < S; ++s) {
      float x = ss[s];
      float sp = log1pf(expf(-fabsf(x))) + fmaxf(x, 0.f);  // softplus
      st[s] = sp; tot += sp;
    }
    for (int s = 0; s < S; ++s) ws[WS_ST + s] = st[s] / tot;
  }
}

#define SPLITJ(H_, J_, V_) { \
  float v_ = (V_); \
  unsigned u1_ = __float_as_uint(v_); \
  float r1_ = v_ - __uint_as_float(u1_ & 0xFFFF0000u); \
  unsigned u2_ = __float_as_uint(r1_); \
  float r2_ = r1_ - __uint_as_float(u2_ & 0xFFFF0000u); \
  unsigned u3_ = __float_as_uint(r2_); \
  a1[H_][J_] = (short)(u1_ >> 16); \
  a2[H_][J_] = (short)(u2_ >> 16); \
  a3[H_][J_] = (short)(u3_ >> 16); }

// MFMA kernel: R22 numerics EXACTLY (6 split terms, libm expf softmax) --
// R25's a2b2 drop was 2^-16-relative, flipped argmaxes. Only scheduling
// change kept: 512 blocks x 16 iters (prologue amortized 2x).
__launch_bounds__(256)
__global__ void k_main(const float* __restrict__ item,
                       const float* __restrict__ ws,    // keys/st + wf
                       const float* __restrict__ bq,
                       float* red,                      // ws (partials out)
                       float* __restrict__ slot_weights,
                       float* __restrict__ selected,
                       int B) {
  __shared__ float red_sum[4][S];
  __shared__ int   red_lw[4][S];

  int t = threadIdx.x;
  int w = t >> 6, lane = t & 63;
  int lrow = lane & 15, g = lane >> 4;
  long base = (long)blockIdx.x * 1024;

  // ---- persistent W fragments: 24 short8 = 96 VGPR ----
  const short8* wfv = (const short8*)(ws + WS_WF);
  short8 B1[2][4], B2[2][4], B3[2][4];
  #pragma unroll
  for (int h = 0; h < 2; ++h)
    #pragma unroll
    for (int nb = 0; nb < 4; ++nb) {
      B1[h][nb] = wfv[(h * 4 + nb) * 64 + lane];
      B2[h][nb] = wfv[512 + (h * 4 + nb) * 64 + lane];
      B3[h][nb] = wfv[1024 + (h * 4 + nb) * 64 + lane];
    }

  float kf[4][4], bqv[4];
  #pragma unroll
  for (int nb = 0; nb < 4; ++nb) {
    bqv[nb] = bq[nb * 16 + lrow];
    #pragma unroll
    for (int s = 0; s < S; ++s) kf[s][nb] = ws[WS_KEYS + s * D + nb * 16 + lrow];
  }
  float s0 = ws[WS_ST + 0], s1 = ws[WS_ST + 1];
  float s2 = ws[WS_ST + 2], s3 = ws[WS_ST + 3];

  float usum[S] = {0.f, 0.f, 0.f, 0.f};
  int   lmax[S] = {-1, -1, -1, -1};

  // ---- prefetch iter 0 ----
  const float4* xr = (const float4*)(item + (base + (long)w * 16 + lrow) * D);
  float4 p0 = xr[g * 2 + 0], p1 = xr[g * 2 + 1];
  float4 p2 = xr[8 + g * 2 + 0], p3 = xr[8 + g * 2 + 1];

  #pragma unroll 1
  for (int it = 0; it < 16; ++it) {
    long r0 = base + it * 64 + (long)w * 16;
    float4 c0 = p0, c1 = p1, c2 = p2, c3 = p3;
    if (it < 15) {                      // uniform-trip prefetch of iter+1
      const float4* xn = (const float4*)(item + (r0 + 64 + lrow) * D);
      p0 = xn[g * 2 + 0]; p1 = xn[g * 2 + 1];
      p2 = xn[8 + g * 2 + 0]; p3 = xn[8 + g * 2 + 1];
    }

    short8 a1[2], a2[2], a3[2];
    SPLITJ(0, 0, c0.x) SPLITJ(0, 1, c0.y) SPLITJ(0, 2, c0.z) SPLITJ(0, 3, c0.w)
    SPLITJ(0, 4, c1.x) SPLITJ(0, 5, c1.y) SPLITJ(0, 6, c1.z) SPLITJ(0, 7, c1.w)
    SPLITJ(1, 0, c2.x) SPLITJ(1, 1, c2.y) SPLITJ(1, 2, c2.z) SPLITJ(1, 3, c2.w)
    SPLITJ(1, 4, c3.x) SPLITJ(1, 5, c3.y) SPLITJ(1, 6, c3.z) SPLITJ(1, 7, c3.w)

    f32x4 acc[4];
    #pragma unroll
    for (int nb = 0; nb < 4; ++nb) acc[nb] = (f32x4){0.f, 0.f, 0.f, 0.f};

    #pragma unroll
    for (int h = 0; h < 2; ++h) {
      #pragma unroll
      for (int nb = 0; nb < 4; ++nb) {
        acc[nb] = __builtin_amdgcn_mfma_f32_16x16x32_bf16(a1[h], B1[h][nb], acc[nb], 0, 0, 0);
        acc[nb] = __builtin_amdgcn_mfma_f32_16x16x32_bf16(a1[h], B2[h][nb], acc[nb], 0, 0, 0);
        acc[nb] = __builtin_amdgcn_mfma_f32_16x16x32_bf16(a2[h], B1[h][nb], acc[nb], 0, 0, 0);
        acc[nb] = __builtin_amdgcn_mfma_f32_16x16x32_bf16(a1[h], B3[h][nb], acc[nb], 0, 0, 0);
        acc[nb] = __builtin_amdgcn_mfma_f32_16x16x32_bf16(a3[h], B1[h][nb], acc[nb], 0, 0, 0);
        acc[nb] = __builtin_amdgcn_mfma_f32_16x16x32_bf16(a2[h], B2[h][nb], acc[nb], 0, 0, 0);
      }
    }

    // epilogue: tanh + partial sims over this lane's 4 rows x 4 slots
    float ps[4][4];
    #pragma unroll
    for (int r_ = 0; r_ < 4; ++r_)
      #pragma unroll
      for (int s = 0; s < S; ++s) ps[r_][s] = 0.f;
    #pragma unroll
    for (int nb = 0; nb < 4; ++nb)
      #pragma unroll
      for (int r_ = 0; r_ < 4; ++r_) {
        float q = TANH1(acc[nb][r_] + bqv[nb]);
        #pragma unroll
        for (int s = 0; s < S; ++s) ps[r_][s] = fmaf(q, kf[s][nb], ps[r_][s]);
      }
    #pragma unroll
    for (int m_ = 1; m_ <= 8; m_ <<= 1)
      #pragma unroll
      for (int r_ = 0; r_ < 4; ++r_)
        #pragma unroll
        for (int s = 0; s < S; ++s) ps[r_][s] += __shfl_xor(ps[r_][s], m_);

    bool act = lrow < 4;
    float q0 = ps[0][0], q1 = ps[0][1], q2 = ps[0][2], q3 = ps[0][3];
    if (lrow == 1)      { q0 = ps[1][0]; q1 = ps[1][1]; q2 = ps[1][2]; q3 = ps[1][3]; }
    else if (lrow == 2) { q0 = ps[2][0]; q1 = ps[2][1]; q2 = ps[2][2]; q3 = ps[2][3]; }
    else if (lrow == 3) { q0 = ps[3][0]; q1 = ps[3][1]; q2 = ps[3][2]; q3 = ps[3][3]; }
    long grow = r0 + g * 4 + lrow;

    if (act) {
      float m = fmaxf(fmaxf(q0, q1), fmaxf(q2, q3));
      float e0 = expf(q0 - m), e1 = expf(q1 - m), e2 = expf(q2 - m), e3 = expf(q3 - m);
      float se = e0 + e1 + e2 + e3;
      float w0 = e0 / se, w1 = e1 / se, w2 = e2 / se, w3 = e3 / se;
      *(float4*)(slot_weights + grow * S) = make_float4(w0, w1, w2, w3);
      float u0 = w0 * s0, u1 = w1 * s1, u2 = w2 * s2, u3 = w3 * s3;
      float us = u0 + u1 + u2 + u3;
      u0 /= us; u1 /= us; u2 /= us; u3 /= us;
      int sel = 0; float best = u0;
      if (u1 > best) { best = u1; sel = 1; }
      if (u2 > best) { best = u2; sel = 2; }
      if (u3 > best) { best = u3; sel = 3; }
      selected[grow] = (float)sel;
      usum[0] += u0; usum[1] += u1; usum[2] += u2; usum[3] += u3;
      #pragma unroll
      for (int s = 0; s < S; ++s)
        if (sel == s && (int)grow > lmax[s]) lmax[s] = (int)grow;
    }
  }

  // ---- block reduction -> plain-store per-block partials (no atomics) ----
  #pragma unroll
  for (int off = 32; off > 0; off >>= 1) {
    #pragma unroll
    for (int s = 0; s < S; ++s) {
      usum[s] += __shfl_down(usum[s], off);
      int m = __shfl_down(lmax[s], off);
      lmax[s] = lmax[s] > m ? lmax[s] : m;
    }
  }
  if (lane == 0) {
    #pragma unroll
    for (int s = 0; s < S; ++s) { red_sum[w][s] = usum[s]; red_lw[w][s] = lmax[s]; }
  }
  __syncthreads();
  if (t < S) {
    float tot = red_sum[0][t] + red_sum[1][t] + red_sum[2][t] + red_sum[3][t];
    int lm = red_lw[0][t];
    if (red_lw[1][t] > lm) lm = red_lw[1][t];
    if (red_lw[2][t] > lm) lm = red_lw[2][t];
    if (red_lw[3][t] > lm) lm = red_lw[3][t];
    float* part = red + WS_PART + (long)blockIdx.x * 8;
    part[t] = tot;
    ((int*)part)[4 + t] = lm;
  }
}

__global__ void k_final(const float* __restrict__ item,
                        const float* __restrict__ slots,
                        const float* __restrict__ usage,
                        const float* __restrict__ Wv,
                        const float* __restrict__ bv,
                        float* ws,
                        float* __restrict__ out_ns,
                        float* __restrict__ out_nu,
                        int B, int nblk) {
  int t = threadIdx.x;  // 256 threads
  int w = t >> 6, lane = t & 63, d = t & 63;
  __shared__ float rs[4][S];
  __shared__ int   rl[4][S];
  __shared__ float s_sums[S];
  __shared__ int   s_lw[S];
  __shared__ float mean[D];
  __shared__ float part4[4][D];

  // ---- phase 1: reduce per-block partials (plain loads) ----
  float ls[S] = {0.f, 0.f, 0.f, 0.f};
  int   ll[S] = {-1, -1, -1, -1};
  const float* part = ws + WS_PART;
  for (int i = t; i < nblk; i += 256) {
    const float* p = part + (long)i * 8;
    ls[0] += p[0]; ls[1] += p[1]; ls[2] += p[2]; ls[3] += p[3];
    const int* pi = (const int*)p + 4;
    ll[0] = ll[0] > pi[0] ? ll[0] : pi[0];
    ll[1] = ll[1] > pi[1] ? ll[1] : pi[1];
    ll[2] = ll[2] > pi[2] ? ll[2] : pi[2];
    ll[3] = ll[3] > pi[3] ? ll[3] : pi[3];
  }
  #pragma unroll
  for (int off = 32; off > 0; off >>= 1) {
    #pragma unroll
    for (int s = 0; s < S; ++s) {
      ls[s] += __shfl_down(ls[s], off);
      int m = __shfl_down(ll[s], off);
      ll[s] = ll[s] > m ? ll[s] : m;
    }
  }
  if (lane == 0) {
    #pragma unroll
    for (int s = 0; s < S; ++s) { rs[w][s] = ls[s]; rl[w][s] = ll[s]; }
  }
  __syncthreads();
  if (t < S) {
    s_sums[t] = rs[0][t] + rs[1][t] + rs[2][t] + rs[3][t];
    int lm = rl[0][t];
    if (rl[1][t] > lm) lm = rl[1][t];
    if (rl[2][t] > lm) lm = rl[2][t];
    if (rl[3][t] > lm) lm = rl[3][t];
    s_lw[t] = lm;
  }
  __syncthreads();

  // ---- phase 2: new_slots / mean / out1 / new_usage ----
  if (w == 0) {
    float nsv[S];
    for (int s = 0; s < S; ++s) {
      int wr = s_lw[s];
      float v = (wr >= 0) ? item[(size_t)wr * D + d] : slots[s * D + d];
      nsv[s] = v;
      out_ns[s * D + d] = v;
    }
    mean[d] = (nsv[0] + nsv[1] + nsv[2] + nsv[3]) * 0.25f;
  }
  __syncthreads();
  float acc = 0.f;
  for (int k = w * 16; k < w * 16 + 16; ++k) acc = fmaf(mean[k], Wv[d * D + k], acc);
  part4[w][d] = acc;
  __syncthreads();
  if (w == 0) {
    float a = part4[0][d] + part4[1][d] + part4[2][d] + part4[3][d] + bv[d];
    ws[WS_OUT1 + d] = tanhf(a);
    if (d < S) out_nu[d] = usage[d] * 0.9f + s_sums[d] / (float)B;
  }
}

__global__ void k_bcast(const float* __restrict__ ws,
                        float4* __restrict__ out, long n4) {
  __shared__ float4 o4[16];
  if (threadIdx.x < 16) o4[threadIdx.x] = ((const float4*)(ws + WS_OUT1))[threadIdx.x];
  __syncthreads();
  long i = (long)blockIdx.x * blockDim.x + threadIdx.x;
  long stride = (long)gridDim.x * blockDim.x;
  for (; i < n4; i += stride) out[i] = o4[i & 15];
}

extern "C" void kernel_launch(void* const* d_in, const int* in_sizes, int n_in,
                              void* d_out, int out_size, void* d_ws, size_t ws_size,
                              hipStream_t stream) {
  const float* item  = (const float*)d_in[0];
  const float* slots = (const float*)d_in[1];
  const float* ss    = (const float*)d_in[2];
  const float* usage = (const float*)d_in[3];
  const float* Wq    = (const float*)d_in[4];
  const float* bq    = (const float*)d_in[5];
  const float* Wk    = (const float*)d_in[6];
  const float* bk    = (const float*)d_in[7];
  const float* Wv    = (const float*)d_in[8];
  const float* bv    = (const float*)d_in[9];
  int B = in_sizes[0] / D;
  float* ws = (float*)d_ws;

  float* out_output       = (float*)d_out;
  float* out_new_slots    = out_output + (size_t)B * D;
  float* out_new_usage    = out_new_slots + S * D;
  float* out_selected     = out_new_usage + S;
  float* out_slot_weights = out_selected + B;

  int nblk = B / 1024;
  k_prep<<<1, 256, 0, stream>>>(slots, ss, Wk, bk, Wq, ws);
  k_main<<<nblk, 256, 0, stream>>>(
      item, ws, bq, ws, out_slot_weights, out_selected, B);
  k_final<<<1, 256, 0, stream>>>(item, slots, usage, Wv, bv, ws,
                                 out_new_slots, out_new_usage, B, nblk);
  long n4 = (long)B * D / 4;
  k_bcast<<<2048, 256, 0, stream>>>(ws, (float4*)out_output, n4);
}